// Round 9
// baseline (92.648 us; speedup 1.0000x reference)
//
#include <hip/hip_runtime.h>

// Problem constants (B, L, D from reference)
#define BB 64
#define LL 4096
#define DD 256
#define D4 (DD / 4)        // float4 per row = 64
#define RPC 32             // rows per wave
#define CPB 4              // waves per block
#define ROWS_PER_BLOCK (RPC * CPB)   // 128
#define BPB (LL / ROWS_PER_BLOCK)    // max slots per batch = 32

// ws layout: [0, 256B): int done-counters[BB]; [4096B, ...): float4 partials[B][BPB][D4]
#define WS_PART_OFF 4096

// ---------------- Fused: partial sums + last-block-done reduction ----------------
// 2048 blocks x 256 threads (8 blocks/CU, 32 waves/CU). Block = 128 rows of one
// batch; 4 waves stream 32 rows each (float4/lane, unroll 8), LDS-combine, wave 0
// writes ONE partial. Then release-fence + per-batch done-counter; the LAST block
// of each batch re-reads that batch's slots (slot order -> bitwise deterministic)
// and writes out[b] = sum / len. No second dispatch, no global tail barrier.
__global__ __launch_bounds__(256) void avg_fused_kernel(
    const float* __restrict__ in,        // [B, L, D]
    const int* __restrict__ len,         // [B] (int32)
    int* __restrict__ cnt,               // [BB] zeroed counters (ws)
    float* __restrict__ part,            // [B, BPB, D] partials (ws)
    float* __restrict__ out)             // [B, D]
{
    const int w    = threadIdx.x >> 6;   // wave 0..3
    const int lane = threadIdx.x & 63;
    const int b    = blockIdx.x / BPB;   // batch (b-major, proven R5/R8)
    const int s    = blockIdx.x % BPB;   // slot within batch

    int lb = len[b];
    if (lb < 1) lb = 1;
    const int nslots = (lb + ROWS_PER_BLOCK - 1) >> 7;   // active blocks, 1..32
    if (s >= nslots) return;             // block-uniform early exit

    const int row0 = s * ROWS_PER_BLOCK + w * RPC;

    float4 acc = make_float4(0.f, 0.f, 0.f, 0.f);
    if (row0 < lb) {
        int n = lb - row0;
        if (n > RPC) n = RPC;
        const float4* __restrict__ base =
            (const float4*)(in + (size_t)b * LL * DD) + (size_t)row0 * D4 + lane;
        #pragma unroll 8
        for (int r = 0; r < n; ++r) {
            float4 v = base[(size_t)r * D4];
            acc.x += v.x; acc.y += v.y; acc.z += v.z; acc.w += v.w;
        }
    }

    // Combine 4 waves -> wave 0
    __shared__ float4 sh[CPB - 1][64];
    if (w > 0) sh[w - 1][lane] = acc;
    __syncthreads();
    if (w != 0) return;

    #pragma unroll
    for (int i = 0; i < CPB - 1; ++i) {
        float4 v = sh[i][lane];
        acc.x += v.x; acc.y += v.y; acc.z += v.z; acc.w += v.w;
    }

    float4* __restrict__ pb = (float4*)part + (size_t)b * BPB * D4;
    pb[(size_t)s * D4 + lane] = acc;

    // Release: partial visible before counter bump (device scope).
    __threadfence();
    int old = 0;
    if (lane == 0) old = atomicAdd(&cnt[b], 1);
    old = __shfl(old, 0, 64);

    if (old == nslots - 1) {
        // Acquire: all partials of batch b visible.
        __threadfence();
        float4 r = make_float4(0.f, 0.f, 0.f, 0.f);
        for (int t = 0; t < nslots; ++t) {
            float4 v = pb[(size_t)t * D4 + lane];
            r.x += v.x; r.y += v.y; r.z += v.z; r.w += v.w;
        }
        const float inv = 1.0f / (float)lb;
        float4 o = make_float4(r.x * inv, r.y * inv, r.z * inv, r.w * inv);
        ((float4*)out)[(size_t)b * D4 + lane] = o;
    }
}

// ---------------- Fallback (tiny ws): zero-out + atomic accumulate ----------------
__global__ void avg_zero_out_kernel(float* __restrict__ out) {
    int i = blockIdx.x * blockDim.x + threadIdx.x;
    if (i < BB * DD) out[i] = 0.f;
}

__global__ __launch_bounds__(64) void avg_atomic_kernel(
    const float* __restrict__ in,
    const int* __restrict__ len,
    float* __restrict__ out)
{
    const int b    = blockIdx.x >> 6;
    const int p    = blockIdx.x & 63;
    const int lane = threadIdx.x;

    int lb = len[b];
    if (lb < 1) lb = 1;
    const int row0 = p * 64;
    int rend = row0 + 64;
    if (rend > lb) rend = (lb > row0) ? lb : row0;
    if (rend <= row0) return;

    float4 acc = make_float4(0.f, 0.f, 0.f, 0.f);
    const float4* __restrict__ base = (const float4*)(in + (size_t)b * LL * DD);
    for (int r = row0; r < rend; ++r) {
        float4 v = base[(size_t)r * D4 + lane];
        acc.x += v.x; acc.y += v.y; acc.z += v.z; acc.w += v.w;
    }
    const float inv = 1.0f / (float)lb;
    float* o = out + (size_t)b * DD + lane * 4;
    atomicAdd(o + 0, acc.x * inv);
    atomicAdd(o + 1, acc.y * inv);
    atomicAdd(o + 2, acc.z * inv);
    atomicAdd(o + 3, acc.w * inv);
}

extern "C" void kernel_launch(void* const* d_in, const int* in_sizes, int n_in,
                              void* d_out, int out_size, void* d_ws, size_t ws_size,
                              hipStream_t stream) {
    const float* in  = (const float*)d_in[0];
    const int*   len = (const int*)d_in[1];
    float*       out = (float*)d_out;

    const size_t ws_needed = WS_PART_OFF + (size_t)BB * BPB * DD * sizeof(float); // ~2 MiB

    if (d_ws != nullptr && ws_size >= ws_needed) {
        int*   cnt  = (int*)d_ws;
        float* part = (float*)((char*)d_ws + WS_PART_OFF);
        // Zero the 64 done-counters (graph-legal async memset node; 256 B).
        hipMemsetAsync(cnt, 0, BB * sizeof(int), stream);
        avg_fused_kernel<<<BB * BPB, 64 * CPB, 0, stream>>>(in, len, cnt, part, out);
    } else {
        avg_zero_out_kernel<<<(BB * DD + 255) / 256, 256, 0, stream>>>(out);
        avg_atomic_kernel<<<BB * 64, 64, 0, stream>>>(in, len, out);
    }
}

// Round 11
// 32.650 us; speedup vs baseline: 2.8376x; 2.8376x over previous
//
#include <hip/hip_runtime.h>

// Problem constants (B, L, D from reference)
#define BB 64
#define LL 4096
#define DD 256
#define D4 (DD / 4)        // float4 per row = 64
#define RPC 32             // rows per wave
#define CPB 4              // waves per block
#define ROWS_PER_BLOCK (RPC * CPB)   // 128
#define BPB (LL / ROWS_PER_BLOCK)    // slots per batch = 32
#define RWAVES 8           // waves per block, phase 2

// Native vector type: __builtin_nontemporal_load requires scalar/pointer/vector
// (HIP_vector_type float4 is a struct and is rejected).
typedef float floatx4 __attribute__((ext_vector_type(4)));

// ---------------- Phase 1: partial sums, block-combined (R8 structure) ----------------
// 2048 blocks x 256 threads (8 blocks/CU = 32 waves/CU). Block = 128 adjacent rows
// of one batch; wave w streams 32 rows (16 B/lane, coalesced, unroll 8 -> 8 loads
// in flight). Input loads are NON-TEMPORAL (use-once stream, nt cache policy);
// partials stored normally so phase 2 hits L2.
__global__ __launch_bounds__(256) void avg_partial_kernel(
    const float* __restrict__ in,        // [B, L, D]
    const int* __restrict__ len,         // [B] (int32)
    float* __restrict__ ws)              // [B, BPB, D]
{
    const int w    = threadIdx.x >> 6;   // wave 0..3
    const int lane = threadIdx.x & 63;
    const int b    = blockIdx.x / BPB;   // batch (b-major, proven R5/R8)
    const int s    = blockIdx.x % BPB;   // slot within batch

    const int lb = len[b];               // >= 1 per reference

    // Whole-block inactive? (block-uniform -> safe early exit; slot never read)
    if (s * ROWS_PER_BLOCK >= lb) return;

    const int row0 = s * ROWS_PER_BLOCK + w * RPC;

    floatx4 acc = (floatx4)(0.f);
    if (row0 < lb) {
        int n = lb - row0;
        if (n > RPC) n = RPC;
        const floatx4* __restrict__ base =
            (const floatx4*)(in + (size_t)b * LL * DD) + (size_t)row0 * D4 + lane;
        #pragma unroll 8
        for (int r = 0; r < n; ++r) {
            floatx4 v = __builtin_nontemporal_load(&base[(size_t)r * D4]);
            acc += v;
        }
    }

    __shared__ floatx4 sh[CPB - 1][64];
    if (w > 0) sh[w - 1][lane] = acc;
    __syncthreads();

    if (w == 0) {
        #pragma unroll
        for (int i = 0; i < CPB - 1; ++i) acc += sh[i][lane];
        ((floatx4*)ws)[((size_t)b * BPB + s) * D4 + lane] = acc;
    }
}

// ---------------- Phase 2: reduce <=32 block partials, divide by length ----------------
__global__ __launch_bounds__(512) void avg_reduce_kernel(
    const float* __restrict__ ws,        // [B, BPB, D]
    const int* __restrict__ len,         // [B]
    float* __restrict__ out)             // [B, D]
{
    const int b    = blockIdx.x;
    const int w    = threadIdx.x >> 6;
    const int lane = threadIdx.x & 63;

    int lb = len[b];
    if (lb < 1) lb = 1;
    const int nslots = (lb + ROWS_PER_BLOCK - 1) / ROWS_PER_BLOCK;  // 1..32

    floatx4 acc = (floatx4)(0.f);
    const floatx4* __restrict__ wsb = (const floatx4*)ws + (size_t)b * BPB * D4;

    #pragma unroll 4
    for (int s = w; s < nslots; s += RWAVES) acc += wsb[(size_t)s * D4 + lane];

    __shared__ floatx4 sh[RWAVES - 1][64];
    if (w > 0) sh[w - 1][lane] = acc;
    __syncthreads();

    if (w == 0) {
        #pragma unroll
        for (int i = 0; i < RWAVES - 1; ++i) acc += sh[i][lane];
        const float inv = 1.0f / (float)lb;
        acc *= inv;
        ((floatx4*)out)[(size_t)b * D4 + lane] = acc;
    }
}

// ---------------- Fallback (tiny ws): zero-out + atomic accumulate ----------------
__global__ void avg_zero_out_kernel(float* __restrict__ out) {
    int i = blockIdx.x * blockDim.x + threadIdx.x;
    if (i < BB * DD) out[i] = 0.f;
}

__global__ __launch_bounds__(64) void avg_atomic_kernel(
    const float* __restrict__ in,
    const int* __restrict__ len,
    float* __restrict__ out)
{
    const int b    = blockIdx.x >> 6;
    const int p    = blockIdx.x & 63;
    const int lane = threadIdx.x;

    int lb = len[b];
    if (lb < 1) lb = 1;
    const int row0 = p * 64;
    int rend = row0 + 64;
    if (rend > lb) rend = (lb > row0) ? lb : row0;
    if (rend <= row0) return;

    floatx4 acc = (floatx4)(0.f);
    const floatx4* __restrict__ base = (const floatx4*)(in + (size_t)b * LL * DD);
    for (int r = row0; r < rend; ++r) acc += base[(size_t)r * D4 + lane];

    const float inv = 1.0f / (float)lb;
    float* o = out + (size_t)b * DD + lane * 4;
    atomicAdd(o + 0, acc.x * inv);
    atomicAdd(o + 1, acc.y * inv);
    atomicAdd(o + 2, acc.z * inv);
    atomicAdd(o + 3, acc.w * inv);
}

extern "C" void kernel_launch(void* const* d_in, const int* in_sizes, int n_in,
                              void* d_out, int out_size, void* d_ws, size_t ws_size,
                              hipStream_t stream) {
    const float* in  = (const float*)d_in[0];
    const int*   len = (const int*)d_in[1];
    float*       out = (float*)d_out;

    const size_t ws_needed = (size_t)BB * BPB * DD * sizeof(float); // 2 MiB

    if (d_ws != nullptr && ws_size >= ws_needed) {
        float* ws = (float*)d_ws;
        avg_partial_kernel<<<BB * BPB, 64 * CPB, 0, stream>>>(in, len, ws);
        avg_reduce_kernel<<<BB, 64 * RWAVES, 0, stream>>>(ws, len, out);
    } else {
        avg_zero_out_kernel<<<(BB * DD + 255) / 256, 256, 0, stream>>>(out);
        avg_atomic_kernel<<<BB * 64, 64, 0, stream>>>(in, len, out);
    }
}

// Round 12
// 29.283 us; speedup vs baseline: 3.1639x; 1.1150x over previous
//
#include <hip/hip_runtime.h>

// Problem constants (B, L, D from reference)
#define BB 64
#define LL 4096
#define DD 256
#define D4 (DD / 4)        // float4 per row = 64
#define RPC 32             // rows per wave
#define CPB 4              // waves per block
#define ROWS_PER_BLOCK (RPC * CPB)   // 128
#define BPB (LL / ROWS_PER_BLOCK)    // slots per batch = 32
#define RWAVES 8           // waves per block, phase 2

typedef float floatx4 __attribute__((ext_vector_type(4)));

// ---------------- Phase 1: partial sums, block-combined (R8 winner) ----------------
// 2048 blocks x 256 threads (8 blocks/CU = 32 waves/CU, max TLP — R5's proven
// lever). Block = 128 adjacent rows of one batch; wave w streams 32 rows
// (16 B/lane, coalesced 1 KiB/wave-load, unroll 8 -> 8 loads in flight).
// Plain cached loads (R11 proved nt regresses). 4 waves LDS-combine; wave 0
// writes ONE partial per block (R8's ws-trim win: 4 MiB round-trip total).
__global__ __launch_bounds__(256) void avg_partial_kernel(
    const float* __restrict__ in,        // [B, L, D]
    const int* __restrict__ len,         // [B] (int32)
    float* __restrict__ ws)              // [B, BPB, D]
{
    const int w    = threadIdx.x >> 6;   // wave 0..3
    const int lane = threadIdx.x & 63;
    const int b    = blockIdx.x / BPB;   // batch (b-major, proven R5/R8)
    const int s    = blockIdx.x % BPB;   // slot within batch

    const int lb = len[b];               // >= 1 per reference

    // Whole-block inactive? (block-uniform -> safe early exit; slot never read)
    if (s * ROWS_PER_BLOCK >= lb) return;

    const int row0 = s * ROWS_PER_BLOCK + w * RPC;

    floatx4 acc = (floatx4)(0.f);
    if (row0 < lb) {
        int n = lb - row0;
        if (n > RPC) n = RPC;
        const floatx4* __restrict__ base =
            (const floatx4*)(in + (size_t)b * LL * DD) + (size_t)row0 * D4 + lane;
        #pragma unroll 8
        for (int r = 0; r < n; ++r) {
            acc += base[(size_t)r * D4];
        }
    }

    __shared__ floatx4 sh[CPB - 1][64];
    if (w > 0) sh[w - 1][lane] = acc;
    __syncthreads();

    if (w == 0) {
        #pragma unroll
        for (int i = 0; i < CPB - 1; ++i) acc += sh[i][lane];
        ((floatx4*)ws)[((size_t)b * BPB + s) * D4 + lane] = acc;
    }
}

// ---------------- Phase 2: reduce <=32 block partials, divide by length ----------------
__global__ __launch_bounds__(512) void avg_reduce_kernel(
    const float* __restrict__ ws,        // [B, BPB, D]
    const int* __restrict__ len,         // [B]
    float* __restrict__ out)             // [B, D]
{
    const int b    = blockIdx.x;
    const int w    = threadIdx.x >> 6;
    const int lane = threadIdx.x & 63;

    int lb = len[b];
    if (lb < 1) lb = 1;
    const int nslots = (lb + ROWS_PER_BLOCK - 1) / ROWS_PER_BLOCK;  // 1..32

    floatx4 acc = (floatx4)(0.f);
    const floatx4* __restrict__ wsb = (const floatx4*)ws + (size_t)b * BPB * D4;

    #pragma unroll 4
    for (int s = w; s < nslots; s += RWAVES) acc += wsb[(size_t)s * D4 + lane];

    __shared__ floatx4 sh[RWAVES - 1][64];
    if (w > 0) sh[w - 1][lane] = acc;
    __syncthreads();

    if (w == 0) {
        #pragma unroll
        for (int i = 0; i < RWAVES - 1; ++i) acc += sh[i][lane];
        const float inv = 1.0f / (float)lb;
        acc *= inv;
        ((floatx4*)out)[(size_t)b * D4 + lane] = acc;
    }
}

// ---------------- Fallback (tiny ws): zero-out + atomic accumulate ----------------
__global__ void avg_zero_out_kernel(float* __restrict__ out) {
    int i = blockIdx.x * blockDim.x + threadIdx.x;
    if (i < BB * DD) out[i] = 0.f;
}

__global__ __launch_bounds__(64) void avg_atomic_kernel(
    const float* __restrict__ in,
    const int* __restrict__ len,
    float* __restrict__ out)
{
    const int b    = blockIdx.x >> 6;
    const int p    = blockIdx.x & 63;
    const int lane = threadIdx.x;

    int lb = len[b];
    if (lb < 1) lb = 1;
    const int row0 = p * 64;
    int rend = row0 + 64;
    if (rend > lb) rend = (lb > row0) ? lb : row0;
    if (rend <= row0) return;

    floatx4 acc = (floatx4)(0.f);
    const floatx4* __restrict__ base = (const floatx4*)(in + (size_t)b * LL * DD);
    for (int r = row0; r < rend; ++r) acc += base[(size_t)r * D4 + lane];

    const float inv = 1.0f / (float)lb;
    float* o = out + (size_t)b * DD + lane * 4;
    atomicAdd(o + 0, acc.x * inv);
    atomicAdd(o + 1, acc.y * inv);
    atomicAdd(o + 2, acc.z * inv);
    atomicAdd(o + 3, acc.w * inv);
}

extern "C" void kernel_launch(void* const* d_in, const int* in_sizes, int n_in,
                              void* d_out, int out_size, void* d_ws, size_t ws_size,
                              hipStream_t stream) {
    const float* in  = (const float*)d_in[0];
    const int*   len = (const int*)d_in[1];
    float*       out = (float*)d_out;

    const size_t ws_needed = (size_t)BB * BPB * DD * sizeof(float); // 2 MiB

    if (d_ws != nullptr && ws_size >= ws_needed) {
        float* ws = (float*)d_ws;
        avg_partial_kernel<<<BB * BPB, 64 * CPB, 0, stream>>>(in, len, ws);
        avg_reduce_kernel<<<BB, 64 * RWAVES, 0, stream>>>(ws, len, out);
    } else {
        avg_zero_out_kernel<<<(BB * DD + 255) / 256, 256, 0, stream>>>(out);
        avg_atomic_kernel<<<BB * 64, 64, 0, stream>>>(in, len, out);
    }
}